// Round 4
// baseline (303.425 us; speedup 1.0000x reference)
//
#include <hip/hip_runtime.h>

#define BB 16
#define MM 1024
#define NN 2048
#define RCAP 64   // max row degree (mean ~22.5; 64 is ~9 sigma)
#define CCAP 48   // max col degree for c>=2 (mean ~10.2; 48 is ~11 sigma)
#define NITER 5
#define NBLK 128
#define NTHR 256

__device__ __forceinline__ float signf(float x) {
    return (x > 0.0f) ? 1.0f : ((x < 0.0f) ? -1.0f : 0.0f);  // jnp.sign
}

// Device-scope grid barrier: monotonic counter, all NBLK blocks arrive.
// Release: per-thread __threadfence() (drain + L2 writeback) before arrival.
// Acquire: relaxed spin + one acquire load (L1 inv) before proceeding.
__device__ __forceinline__ void grid_barrier(int* cnt, int target) {
    __threadfence();
    __syncthreads();
    if (threadIdx.x == 0) {
        __hip_atomic_fetch_add(cnt, 1, __ATOMIC_RELEASE, __HIP_MEMORY_SCOPE_AGENT);
        while (__hip_atomic_load(cnt, __ATOMIC_RELAXED, __HIP_MEMORY_SCOPE_AGENT) < target)
            __builtin_amdgcn_s_sleep(2);
        (void)__hip_atomic_load(cnt, __ATOMIC_ACQUIRE, __HIP_MEMORY_SCOPE_AGENT);
    }
    __syncthreads();
}

// Everything in one launch: build edge lists, then 5 decode iterations with
// grid barriers between the check (A) and variable (B) phases.
__global__ __launch_bounds__(NTHR)
void decode_all(const float* __restrict__ soft_in,
                const int4* __restrict__ H4,
                const float* __restrict__ wptr,
                float* __restrict__ out,
                int* __restrict__ cnt,
                int* __restrict__ row_deg, int* __restrict__ col_deg,
                float* __restrict__ heavy,               // [NITER][BB][2]
                unsigned short* __restrict__ row_cols,
                unsigned short* __restrict__ col_rows,
                float4* __restrict__ stats,              // [BB][MM]
                float* __restrict__ soft_buf) {          // [BB][NN]
    __shared__ float4 s_st[MM];          // 16 KB: stats in phase B, soft (8 KB) in phase A
    __shared__ float s_red[8];
    float* s_soft = (float*)s_st;

    const int blk = blockIdx.x, t = threadIdx.x;
    const int lane = t & 63, wv = t >> 6;
    const float norm = log1pf(expf(wptr[0]));            // softplus(w)

    // ---- Build CSR rows (all cols) + CSC cols (c>=2). Cols 0,1 are all-ones. ----
    for (int idx = blk * NTHR + t; idx < MM * NN / 4; idx += NBLK * NTHR) {
        int4 h = H4[idx];
        int base = idx << 2;
        int m = base >> 11, c0 = base & (NN - 1);
        int hv[4] = {h.x, h.y, h.z, h.w};
#pragma unroll
        for (int k = 0; k < 4; ++k) {
            if (hv[k]) {
                int c = c0 + k;
                int j = atomicAdd(&row_deg[m], 1);
                if (j < RCAP) row_cols[m * RCAP + j] = (unsigned short)c;
                if (c >= 2) {
                    int j2 = atomicAdd(&col_deg[c], 1);
                    if (j2 < CCAP) col_rows[c * CCAP + j2] = (unsigned short)m;
                }
            }
        }
    }
    int bar = 0;
    grid_barrier(cnt, ++bar * NBLK);

    // ---- Hoist per-thread static metadata (constant after build). ----
    // Phase A identity (blocks 0..63): row m of batch ba.
    const int ba = blk >> 2;
    const int m = ((blk & 3) << 8) + t;
    const int rdeg = (blk < 64) ? min(row_deg[m], RCAP) : 0;
    const unsigned short* rc = row_cols + m * RCAP;
    // Phase B identity (all blocks): col n of batch bb.
    const int bb = blk >> 3;
    const int n = ((blk & 7) << 8) + t;
    const int cd = (n >= 2) ? min(col_deg[n], CCAP) : 0;
    const unsigned short* cl = col_rows + n * CCAP;

    const float* src = soft_in;
    for (int it = 0; it < NITER; ++it) {
        // ---- Phase A: check-node update (blocks 0..63) ----
        if (blk < 64) {
            const float4* src4 = (const float4*)(src + ba * NN);
            float4* s4 = (float4*)s_soft;
            s4[t] = src4[t];
            s4[t + 256] = src4[t + 256];
            __syncthreads();

            float sgn = 1.0f, mn = 1e30f, sub = 1e30f;
            for (int j = 0; j < rdeg; ++j) {
                float x = s_soft[rc[j]];
                sgn *= signf(x);
                float a = fabsf(x);
                if (a < mn) { sub = mn; mn = a; }
                else if (a < sub) { sub = a; }
            }
            const float ns = norm * sgn;
            stats[ba * MM + m] = make_float4(ns, mn, sub, 0.0f);

            // cv contributions to heavy cols 0,1 (present in every row).
            float x0 = s_soft[0], x1 = s_soft[1];
            float cv0 = ns * ((fabsf(x0) > mn) ? mn : sub) * signf(x0);
            float cv1 = ns * ((fabsf(x1) > mn) ? mn : sub) * signf(x1);
#pragma unroll
            for (int off = 32; off > 0; off >>= 1) {
                cv0 += __shfl_down(cv0, off);
                cv1 += __shfl_down(cv1, off);
            }
            if (lane == 0) { s_red[wv] = cv0; s_red[4 + wv] = cv1; }
            __syncthreads();
            if (t == 0) {
                float* hv = heavy + (it * BB + ba) * 2;
                atomicAdd(&hv[0], s_red[0] + s_red[1] + s_red[2] + s_red[3]);
                atomicAdd(&hv[1], s_red[4] + s_red[5] + s_red[6] + s_red[7]);
            }
        }
        grid_barrier(cnt, ++bar * NBLK);

        // ---- Phase B: variable-node update (all 128 blocks) ----
        const float4* stb = stats + bb * MM;
#pragma unroll
        for (int i = 0; i < 4; ++i) s_st[t + 256 * i] = stb[t + 256 * i];
        __syncthreads();

        float* dst = (it == NITER - 1) ? out : soft_buf;
        float result;
        if (n >= 2) {
            float x = src[bb * NN + n];
            float a = fabsf(x), sx = signf(x), acc = 0.0f;
            for (int j = 0; j < cd; ++j) {
                float4 s = s_st[cl[j]];
                acc += s.x * ((a > s.y) ? s.y : s.z) * sx;
            }
            result = soft_in[bb * NN + n] + acc;
        } else {
            result = soft_in[bb * NN + n] + heavy[(it * BB + bb) * 2 + n];
        }
        dst[bb * NN + n] = result;

        src = soft_buf;
        if (it < NITER - 1) grid_barrier(cnt, ++bar * NBLK);
    }
}

extern "C" void kernel_launch(void* const* d_in, const int* in_sizes, int n_in,
                              void* d_out, int out_size, void* d_ws, size_t ws_size,
                              hipStream_t stream) {
    const float* soft_in = (const float*)d_in[0];
    const int*   H       = (const int*)d_in[1];
    // d_in[2] = labels (unused by forward reference)
    const float* w       = (const float*)d_in[3];

    char* ws = (char*)d_ws;
    int*   cnt      = (int*)ws;                               // 64 B slot
    int*   row_deg  = (int*)(ws + 64);                        // 4 KB
    int*   col_deg  = (int*)(ws + 64 + 4096);                 // 8 KB
    float* heavy    = (float*)(ws + 64 + 4096 + 8192);        // 640 B
    // zero region ends at 12992; round up to 13056
    unsigned short* row_cols = (unsigned short*)(ws + 13056);            // 128 KB
    unsigned short* col_rows = (unsigned short*)(ws + 13056 + 131072);   // 192 KB
    float4* stats   = (float4*)(ws + 13056 + 131072 + 196608);           // 256 KB
    float*  soft_buf = (float*)(ws + 13056 + 131072 + 196608 + 262144);  // 128 KB

    hipMemsetAsync(ws, 0, 13056, stream);   // cnt + degrees + heavy
    decode_all<<<NBLK, NTHR, 0, stream>>>(soft_in, (const int4*)H, w,
                                          (float*)d_out, cnt, row_deg, col_deg,
                                          heavy, row_cols, col_rows, stats, soft_buf);
}

// Round 5
// 164.025 us; speedup vs baseline: 1.8499x; 1.8499x over previous
//
#include <hip/hip_runtime.h>

#define BB 16
#define MM 1024
#define NN 2048
#define RCAP 64   // max row degree capacity (mean ~22.5)
#define CCAP 48   // max col degree capacity for c>=2 (mean ~10.2)
#define INFF __builtin_inff()

typedef unsigned short u16;

__device__ __forceinline__ float signf(float x) {
    return (x > 0.0f) ? 1.0f : ((x < 0.0f) ? -1.0f : 0.0f);  // jnp.sign
}

// One pass over H: CSR row lists (all cols) + CSC col lists (cols>=2).
// Cols 0,1 are all-ones by construction (H[:, :2] = 1) -> handled analytically.
__global__ void build_lists(const int4* __restrict__ H4,
                            int* __restrict__ row_deg, int* __restrict__ col_deg,
                            u16* __restrict__ row_cols, u16* __restrict__ col_rows) {
    int idx = blockIdx.x * blockDim.x + threadIdx.x;
    if (idx >= MM * NN / 4) return;
    int4 h = H4[idx];
    int base = idx << 2;
    int m = base >> 11, c0 = base & (NN - 1);
    int hv[4] = {h.x, h.y, h.z, h.w};
#pragma unroll
    for (int k = 0; k < 4; ++k) {
        if (hv[k]) {
            int c = c0 + k;
            int j = atomicAdd(&row_deg[m], 1);
            if (j < RCAP) row_cols[m * RCAP + j] = (u16)c;
            if (c >= 2) {
                int j2 = atomicAdd(&col_deg[c], 1);
                if (j2 < CCAP) col_rows[c * CCAP + j2] = (u16)m;
            }
        }
    }
}

// Row stats {norm*sign-product, min|x|, 2nd-min|x|} gathered from LDS soft.
// Indices loaded 8-at-a-time (one int4 per chunk); tail masked via select.
__device__ __forceinline__ float4 row_stat(const float* s_soft, const u16* rc,
                                           int deg, float norm) {
    float sgn = 1.0f, mn = INFF, sub = INFF;
    for (int jb = 0; jb < deg; jb += 8) {
        int4 iv = *(const int4*)(rc + jb);          // 8 u16 indices, 16B aligned
        const u16* ip = (const u16*)&iv;
#pragma unroll
        for (int k = 0; k < 8; ++k) {
            float x = s_soft[ip[k] & (NN - 1)];
            x = (jb + k < deg) ? x : INFF;          // neutral: sign=+1, |x|=inf
            sgn *= signf(x);
            float a = fabsf(x);
            if (a < mn) { sub = mn; mn = a; }
            else if (a < sub) sub = a;
        }
    }
    return make_float4(norm * sgn, mn, sub, 0.0f);
}

// Sum of cv over a column's rows, stats gathered from LDS.
__device__ __forceinline__ float col_acc(const float4* s_st, const u16* cl,
                                         int deg, float x) {
    float a = fabsf(x), sx = signf(x), acc = 0.0f;
    for (int jb = 0; jb < deg; jb += 8) {
        int4 iv = *(const int4*)(cl + jb);
        const u16* ip = (const u16*)&iv;
#pragma unroll
        for (int k = 0; k < 8; ++k) {
            float4 s = s_st[ip[k] & (MM - 1)];
            float cv = s.x * ((a > s.y) ? s.y : s.z) * sx;
            acc += (jb + k < deg) ? cv : 0.0f;
        }
    }
    return acc;
}

// Block-wide (256 threads) reduction of two floats; result broadcast to all.
__device__ __forceinline__ void block_reduce2(float c0, float c1, float* s_red,
                                              int t, float& r0, float& r1) {
    __syncthreads();                                 // protect s_red reuse
#pragma unroll
    for (int off = 32; off; off >>= 1) { c0 += __shfl_down(c0, off); c1 += __shfl_down(c1, off); }
    int lane = t & 63, wv = t >> 6;
    if (lane == 0) { s_red[wv] = c0; s_red[4 + wv] = c1; }
    __syncthreads();
    r0 = s_red[0] + s_red[1] + s_red[2] + s_red[3];
    r1 = s_red[4] + s_red[5] + s_red[6] + s_red[7];
}

// Iteration 1 check-node pass: stats1 from soft_in. 64 blocks = 16b x 4 chunks.
__global__ __launch_bounds__(256)
void stats_first(const float* __restrict__ soft_in,
                 const int* __restrict__ row_deg, const u16* __restrict__ row_cols,
                 float4* __restrict__ stats_out, const float* __restrict__ wptr) {
    __shared__ float s_soft[NN];
    const int b = blockIdx.x >> 2, t = threadIdx.x;
    const int m = ((blockIdx.x & 3) << 8) + t;
    const float norm = log1pf(expf(wptr[0]));
    const float4* sp = (const float4*)(soft_in + b * NN);
    float4* d = (float4*)s_soft;
    d[t] = sp[t]; d[t + 256] = sp[t + 256];
    __syncthreads();
    stats_out[b * MM + m] = row_stat(s_soft, row_cols + m * RCAP,
                                     min(row_deg[m], RCAP), norm);
}

// Fused iteration: recompute soft(it-1) = soft_in + scatter(stats_prev, soft_old)
// redundantly per block (B-part), then stats(it) for this block's 256 rows (A-part).
// 64 blocks = 16 b x 4 row-chunks. Chunk 0 also writes soft(it-1) to global.
__global__ __launch_bounds__(256)
void iter_fused(const float* __restrict__ soft_in,
                const float* __restrict__ soft_old,      // soft(it-2)
                const float4* __restrict__ stats_prev,   // stats(it-1)
                float4* __restrict__ stats_new,          // stats(it)
                float* __restrict__ soft_cur_out,        // soft(it-1)
                const int* __restrict__ row_deg, const u16* __restrict__ row_cols,
                const int* __restrict__ col_deg, const u16* __restrict__ col_rows,
                const float* __restrict__ wptr) {
    __shared__ float4 s_st[MM];     // 16 KB
    __shared__ float s_old[NN];     // 8 KB
    __shared__ float s_new[NN];     // 8 KB
    __shared__ float s_red[8];
    const int b = blockIdx.x >> 2, t = threadIdx.x, chunk = blockIdx.x & 3;
    const float norm = log1pf(expf(wptr[0]));

    {   // stage stats_prev[b] (16 KB) + soft_old[b] (8 KB)
        const float4* sp = stats_prev + b * MM;
#pragma unroll
        for (int i = 0; i < 4; ++i) s_st[t + 256 * i] = sp[t + 256 * i];
        const float4* so = (const float4*)(soft_old + b * NN);
        float4* d = (float4*)s_old;
        d[t] = so[t]; d[t + 256] = so[t + 256];
    }
    __syncthreads();

    // ---- B-part: soft(it-1) for all 2048 cols (8 per thread) ----
    // Heavy cols 0,1 (every row): 4 rows per thread, block-reduce.
    float c0 = 0.0f, c1 = 0.0f;
    {
        float x0 = s_old[0], x1 = s_old[1];
        float a0 = fabsf(x0), sx0 = signf(x0), a1 = fabsf(x1), sx1 = signf(x1);
#pragma unroll
        for (int i = 0; i < 4; ++i) {
            float4 s = s_st[t + 256 * i];
            c0 += s.x * ((a0 > s.y) ? s.y : s.z) * sx0;
            c1 += s.x * ((a1 > s.y) ? s.y : s.z) * sx1;
        }
    }
    float r0, r1;
    block_reduce2(c0, c1, s_red, t, r0, r1);

    float vals[8];
#pragma unroll
    for (int i = 0; i < 8; ++i) {
        int n = t + 256 * i;
        if (n >= 2) {
            vals[i] = soft_in[b * NN + n] +
                      col_acc(s_st, col_rows + n * CCAP, min(col_deg[n], CCAP), s_old[n]);
        } else {
            vals[i] = soft_in[b * NN + n] + ((n == 0) ? r0 : r1);
        }
    }
    __syncthreads();
#pragma unroll
    for (int i = 0; i < 8; ++i) s_new[t + 256 * i] = vals[i];
    __syncthreads();

    if (chunk == 0) {   // one copy of soft(it-1) to global for the next kernel
        const float4* sn = (const float4*)s_new;
        float4* o = (float4*)(soft_cur_out + b * NN);
        o[t] = sn[t]; o[t + 256] = sn[t + 256];
    }

    // ---- A-part: stats(it) for this block's 256 rows ----
    const int m = (chunk << 8) + t;
    stats_new[b * MM + m] = row_stat(s_new, row_cols + m * RCAP,
                                     min(row_deg[m], RCAP), norm);
}

// Final: soft4 = soft_in + scatter(stats4, soft3); stats5 in-LDS; out = soft5.
// 128 blocks = 16 b x 8 col-chunks (256 output cols each).
__global__ __launch_bounds__(256)
void final_fused(const float* __restrict__ soft_in,
                 const float* __restrict__ soft_old,      // soft3
                 const float4* __restrict__ stats_prev,   // stats4
                 float* __restrict__ out,
                 const int* __restrict__ row_deg, const u16* __restrict__ row_cols,
                 const int* __restrict__ col_deg, const u16* __restrict__ col_rows,
                 const float* __restrict__ wptr) {
    __shared__ float4 s_st[MM];
    __shared__ float s_old[NN];
    __shared__ float s_new[NN];
    __shared__ float s_red[8];
    const int b = blockIdx.x >> 3, t = threadIdx.x, chunk = blockIdx.x & 7;
    const float norm = log1pf(expf(wptr[0]));

    {
        const float4* sp = stats_prev + b * MM;
#pragma unroll
        for (int i = 0; i < 4; ++i) s_st[t + 256 * i] = sp[t + 256 * i];
        const float4* so = (const float4*)(soft_old + b * NN);
        float4* d = (float4*)s_old;
        d[t] = so[t]; d[t + 256] = so[t + 256];
    }
    __syncthreads();

    // ---- soft4 (full, 8 cols/thread) ----
    float c0 = 0.0f, c1 = 0.0f;
    {
        float x0 = s_old[0], x1 = s_old[1];
        float a0 = fabsf(x0), sx0 = signf(x0), a1 = fabsf(x1), sx1 = signf(x1);
#pragma unroll
        for (int i = 0; i < 4; ++i) {
            float4 s = s_st[t + 256 * i];
            c0 += s.x * ((a0 > s.y) ? s.y : s.z) * sx0;
            c1 += s.x * ((a1 > s.y) ? s.y : s.z) * sx1;
        }
    }
    float r0, r1;
    block_reduce2(c0, c1, s_red, t, r0, r1);

    float vals[8];
#pragma unroll
    for (int i = 0; i < 8; ++i) {
        int n = t + 256 * i;
        if (n >= 2) {
            vals[i] = soft_in[b * NN + n] +
                      col_acc(s_st, col_rows + n * CCAP, min(col_deg[n], CCAP), s_old[n]);
        } else {
            vals[i] = soft_in[b * NN + n] + ((n == 0) ? r0 : r1);
        }
    }
    __syncthreads();
#pragma unroll
    for (int i = 0; i < 8; ++i) s_new[t + 256 * i] = vals[i];
    __syncthreads();

    // ---- stats5 in-LDS (overwrite s_st; stats4 fully consumed), 4 rows/thread ----
    float4 st5[4];
#pragma unroll
    for (int i = 0; i < 4; ++i) {
        int m = t + 256 * i;
        st5[i] = row_stat(s_new, row_cols + m * RCAP, min(row_deg[m], RCAP), norm);
    }
    __syncthreads();
#pragma unroll
    for (int i = 0; i < 4; ++i) s_st[t + 256 * i] = st5[i];
    __syncthreads();

    // ---- out = soft5 for this block's 256 cols ----
    float h0 = 0.0f, h1 = 0.0f;
    {
        float x0 = s_new[0], x1 = s_new[1];
        float a0 = fabsf(x0), sx0 = signf(x0), a1 = fabsf(x1), sx1 = signf(x1);
#pragma unroll
        for (int i = 0; i < 4; ++i) {
            float4 s = s_st[t + 256 * i];
            h0 += s.x * ((a0 > s.y) ? s.y : s.z) * sx0;
            h1 += s.x * ((a1 > s.y) ? s.y : s.z) * sx1;
        }
    }
    float q0, q1;
    block_reduce2(h0, h1, s_red, t, q0, q1);

    const int n = (chunk << 8) + t;
    float res;
    if (n >= 2) {
        res = soft_in[b * NN + n] +
              col_acc(s_st, col_rows + n * CCAP, min(col_deg[n], CCAP), s_new[n]);
    } else {
        res = soft_in[b * NN + n] + ((n == 0) ? q0 : q1);
    }
    out[b * NN + n] = res;
}

extern "C" void kernel_launch(void* const* d_in, const int* in_sizes, int n_in,
                              void* d_out, int out_size, void* d_ws, size_t ws_size,
                              hipStream_t stream) {
    const float* soft_in = (const float*)d_in[0];
    const int*   H       = (const int*)d_in[1];
    // d_in[2] = labels (unused by forward reference)
    const float* w       = (const float*)d_in[3];
    float* out = (float*)d_out;

    char* ws = (char*)d_ws;
    int* row_deg = (int*)ws;                                   //       0, 4 KB
    int* col_deg = (int*)(ws + 4096);                          //    4096, 8 KB
    u16* row_cols = (u16*)(ws + 12288);                        //   12288, 128 KB
    u16* col_rows = (u16*)(ws + 143360);                       //  143360, 192 KB
    float4* statsA = (float4*)(ws + 339968);                   //  339968, 256 KB
    float4* statsB = (float4*)(ws + 602112);                   //  602112, 256 KB
    float* softX = (float*)(ws + 864256);                      //  864256, 128 KB
    float* softY = (float*)(ws + 995328);                      //  995328, 128 KB

    hipMemsetAsync(ws, 0, 12288, stream);                      // row_deg + col_deg
    build_lists<<<(MM * NN / 4 + 255) / 256, 256, 0, stream>>>(
        (const int4*)H, row_deg, col_deg, row_cols, col_rows);

    // stats1 from soft0 = soft_in
    stats_first<<<64, 256, 0, stream>>>(soft_in, row_deg, row_cols, statsA, w);
    // it=2: soft1 = f(stats1, soft0=soft_in); stats2
    iter_fused<<<64, 256, 0, stream>>>(soft_in, soft_in, statsA, statsB, softX,
                                       row_deg, row_cols, col_deg, col_rows, w);
    // it=3: soft2 = f(stats2, soft1); stats3
    iter_fused<<<64, 256, 0, stream>>>(soft_in, softX, statsB, statsA, softY,
                                       row_deg, row_cols, col_deg, col_rows, w);
    // it=4: soft3 = f(stats3, soft2); stats4
    iter_fused<<<64, 256, 0, stream>>>(soft_in, softY, statsA, statsB, softX,
                                       row_deg, row_cols, col_deg, col_rows, w);
    // final: soft4 = f(stats4, soft3); stats5 in-LDS; out = soft5
    final_fused<<<128, 256, 0, stream>>>(soft_in, softX, statsB, out,
                                         row_deg, row_cols, col_deg, col_rows, w);
}